// Round 3
// baseline (234.176 us; speedup 1.0000x reference)
//
#include <hip/hip_runtime.h>
#include <cstddef>

#define HW 16384

typedef short s8v __attribute__((ext_vector_type(8)));
typedef short s4v __attribute__((ext_vector_type(4)));
typedef float f4v __attribute__((ext_vector_type(4)));

__device__ inline short f2b(float x) {
    union { float f; unsigned u; } v; v.f = x;
    unsigned r = v.u + 0x7fff + ((v.u >> 16) & 1);
    return (short)(r >> 16);
}
// truncating bf16 — for lo residuals only (error ~2^-17 of value)
__device__ inline short f2bt(float x) {
    union { float f; unsigned u; } v; v.f = x;
    return (short)(v.u >> 16);
}
__device__ inline float b2f(short h) {
    union { unsigned u; float f; } v;
    v.u = ((unsigned)(unsigned short)h) << 16;
    return v.f;
}

// Barrier that does NOT drain vmcnt: LDS hazards only need lgkmcnt(0).
__device__ inline void bar_lgkm() {
    asm volatile("s_waitcnt lgkmcnt(0)\n\ts_barrier" ::: "memory");
}

// ---------------- k_prep_w: weights -> chunk-tiled bf16 hi/lo ----------------
__global__ __launch_bounds__(256) void k_prep_w(
    const float* __restrict__ w1, const float* __restrict__ wv,
    const float* __restrict__ w2,
    short* __restrict__ Wthi, short* __restrict__ Wtlo,
    short* __restrict__ w2thi, short* __restrict__ w2tlo)
{
    int tid = blockIdx.x * 256 + threadIdx.x;   // 0..147455
    if (tid < 131072) {
        int c = tid >> 14, r = tid & 16383, ch = r >> 5, kk = r & 31;
        float f = (ch < 256) ? w1[ch * 256 + c * 32 + kk]
                             : wv[(ch - 256) * 256 + c * 32 + kk];
        short hi = f2b(f);
        Wthi[tid] = hi;
        if (ch < 256) Wtlo[(c * 256 + ch) * 32 + kk] = f2b(f - b2f(hi));
    } else {
        int o = tid - 131072;                   // 0..16383
        int c = o >> 11, r = o & 2047, dir = r >> 5, kk = r & 31;
        float f = w2[dir * 256 + c * 32 + kk];
        short hi = f2b(f);
        w2thi[o] = hi;
        w2tlo[o] = f2b(f - b2f(hi));
    }
}

// ---------------- k_mega: fused h(split) + value + flow per 64-px block ------
// OCCUPANCY RESTRUCTURE: 512 threads / 8 waves per 64-px block. Wave w owns
// h-ch [32w,32w+32) (split hi/lo, 3 MFMA) + value-ch [32w,32w+32) (hi only).
// acc = 16 f4v = 64 regs -> total <=128/wave -> 4 waves/SIMD (16 waves/CU,
// 2 blocks x 8 waves; LDS 69632 x2 = 139 KB). TLP now hides weight-L2 and
// LDS latency that 2 waves/SIMD could not (R1/R2 evidence).
__global__ __launch_bounds__(512, 4) void k_mega(
    const float* __restrict__ u,
    const short* __restrict__ Wthi, const short* __restrict__ Wtlo,
    const short* __restrict__ w2thi, const short* __restrict__ w2tlo,
    const float* __restrict__ b1, const float* __restrict__ bv,
    const float* __restrict__ b2,
    unsigned short* __restrict__ vbuf, float* __restrict__ flow)
{
    __shared__ __attribute__((aligned(16))) char smem[69632];
    short* T1h = (short*)smem;               // 64ch x 68, 8704 B
    short* T1l = T1h + 4352;                 // ends 17408
    short* T2h = (short*)(smem + 17408);     // 64px x 72, 9216 B
    short* T2l = T2h + 4608;                 // ends 35840
    short* vt  = (short*)smem;               // 64px x 272 = 34816 B (post K-loop)
    short* hhi = (short*)smem;               // 34816 B (post value store)
    short* hlo = (short*)(smem + 34816);     // ends 69632

    const int t = threadIdx.x;               // 0..511
    const int l = t & 63;
    const int w = t >> 6;                    // wave 0..7
    const int lr = l & 15;
    const int quad = l >> 4;
    const int quad8 = quad * 8;
    const int pt = blockIdx.x * 64;
    const int b  = pt >> 14;
    const int p0 = pt & 16383;
    const float* ub = u + (size_t)b * 256 * HW + p0;

    f4v acc_h[2][4], acc_v[2][4];
    #pragma unroll
    for (int i = 0; i < 2; ++i)
        #pragma unroll
        for (int j = 0; j < 4; ++j) {
            acc_h[i][j] = (f4v){0.f, 0.f, 0.f, 0.f};
            acc_v[i][j] = (f4v){0.f, 0.f, 0.f, 0.f};
        }

    float4 cur[2];
    auto loadU = [&](int pr) {
        #pragma unroll
        for (int i = 0; i < 2; ++i) {
            int idx = t + 512 * i;
            int ch = idx >> 4, px4 = (idx & 15) * 4;
            cur[i] = *reinterpret_cast<const float4*>(
                ub + (size_t)(pr * 64 + ch) * HW + px4);
        }
    };
    // stage A: convert+split cur -> T1 [ch][px] (stride 68)
    auto stageA = [&]() {
        #pragma unroll
        for (int i = 0; i < 2; ++i) {
            int idx = t + 512 * i;
            int ch = idx >> 4, px4 = (idx & 15) * 4;
            float4 v = cur[i];
            short h0 = f2b(v.x), h1 = f2b(v.y), h2 = f2b(v.z), h3 = f2b(v.w);
            s4v hv = {h0, h1, h2, h3};
            s4v lv = {f2bt(v.x - b2f(h0)), f2bt(v.y - b2f(h1)),
                      f2bt(v.z - b2f(h2)), f2bt(v.w - b2f(h3))};
            *reinterpret_cast<s4v*>(T1h + ch * 68 + px4) = hv;
            *reinterpret_cast<s4v*>(T1l + ch * 68 + px4) = lv;
        }
    };
    // stage B: transpose T1 -> T2 [px][k] (stride 72). Wave w handles
    // k4 slices {w, w+8} for all 64 px (px = lane).
    auto stageB = [&]() {
        #pragma unroll
        for (int part = 0; part < 2; ++part) {
            const short* src = part ? T1l : T1h;
            short* dst = part ? T2l : T2h;
            #pragma unroll
            for (int j = 0; j < 2; ++j) {
                int k4 = w + 8 * j;
                s4v v = { src[(4 * k4 + 0) * 68 + l],
                          src[(4 * k4 + 1) * 68 + l],
                          src[(4 * k4 + 2) * 68 + l],
                          src[(4 * k4 + 3) * 68 + l] };
                *reinterpret_cast<s4v*>(dst + l * 72 + 4 * k4) = v;
            }
        }
    };

    loadU(0);
    for (int pair = 0; pair < 4; ++pair) {
        stageA();
        bar_lgkm();
        stageB();
        bar_lgkm();
        if (pair < 3) loadU(pair + 1);   // overlaps MFMA (vmcnt, not drained)
        #pragma unroll
        for (int s = 0; s < 2; ++s) {
            int c = pair * 2 + s;
            s8v bh4[4], bl4[4];
            #pragma unroll
            for (int j = 0; j < 4; ++j) {
                bh4[j] = *reinterpret_cast<const s8v*>(T2h + (16 * j + lr) * 72 + s * 32 + quad8);
                bl4[j] = *reinterpret_cast<const s8v*>(T2l + (16 * j + lr) * 72 + s * 32 + quad8);
            }
            #pragma unroll
            for (int i = 0; i < 2; ++i) {
                const size_t wb = ((size_t)c * 512 + 32 * w + 16 * i + lr) * 32 + quad8;
                s8v ahi = *reinterpret_cast<const s8v*>(Wthi + wb);
                s8v av  = *reinterpret_cast<const s8v*>(Wthi + wb + 256 * 32);
                s8v alo = *reinterpret_cast<const s8v*>(
                    Wtlo + ((size_t)c * 256 + 32 * w + 16 * i + lr) * 32 + quad8);
                #pragma unroll
                for (int j = 0; j < 4; ++j) {
                    acc_h[i][j] = __builtin_amdgcn_mfma_f32_16x16x32_bf16(ahi, bh4[j], acc_h[i][j], 0, 0, 0);
                    acc_h[i][j] = __builtin_amdgcn_mfma_f32_16x16x32_bf16(ahi, bl4[j], acc_h[i][j], 0, 0, 0);
                    acc_h[i][j] = __builtin_amdgcn_mfma_f32_16x16x32_bf16(alo, bh4[j], acc_h[i][j], 0, 0, 0);
                    acc_v[i][j] = __builtin_amdgcn_mfma_f32_16x16x32_bf16(av,  bh4[j], acc_v[i][j], 0, 0, 0);
                }
            }
        }
        bar_lgkm();   // T2 reads done before next pair's T1/T2 writes
    }

    // ---- value epilogue: accs -> vt LDS -> head-major bf16 stores ----
    #pragma unroll
    for (int i = 0; i < 2; ++i) {
        float4 bias = *reinterpret_cast<const float4*>(bv + 32 * w + 16 * i + 4 * quad);
        #pragma unroll
        for (int j = 0; j < 4; ++j) {
            int px = 16 * j + lr;
            s4v pk = { f2b(acc_v[i][j][0] + bias.x), f2b(acc_v[i][j][1] + bias.y),
                       f2b(acc_v[i][j][2] + bias.z), f2b(acc_v[i][j][3] + bias.w) };
            *reinterpret_cast<s4v*>(vt + px * 272 + 32 * w + 16 * i + 4 * quad) = pk;
        }
    }
    bar_lgkm();
    {
        // vbuf layout: [(b*32+head)][pix][8ch] -> 16B per (head,pixel)
        int px = t >> 3;              // 0..63
        int hg = t & 7;               // 4 heads per thread
        size_t pix = (size_t)p0 + px;
        #pragma unroll
        for (int e = 0; e < 4; ++e) {
            int hh = hg + 8 * e;
            s8v vv = *reinterpret_cast<const s8v*>(vt + px * 272 + hh * 8);
            *reinterpret_cast<s8v*>(
                vbuf + ((((size_t)(b * 32 + hh)) << 14) + pix) * 8) = vv;
        }
    }
    bar_lgkm();   // vt reads done before h overwrites

    // ---- h epilogue: bias+relu, split -> hhi/hlo LDS [px][272] ----
    #pragma unroll
    for (int i = 0; i < 2; ++i) {
        float4 bias = *reinterpret_cast<const float4*>(b1 + 32 * w + 16 * i + 4 * quad);
        #pragma unroll
        for (int j = 0; j < 4; ++j) {
            int px = 16 * j + lr;
            float v0 = fmaxf(acc_h[i][j][0] + bias.x, 0.f);
            float v1 = fmaxf(acc_h[i][j][1] + bias.y, 0.f);
            float v2 = fmaxf(acc_h[i][j][2] + bias.z, 0.f);
            float v3 = fmaxf(acc_h[i][j][3] + bias.w, 0.f);
            short h0 = f2b(v0), h1 = f2b(v1), h2 = f2b(v2), h3 = f2b(v3);
            s4v hv = {h0, h1, h2, h3};
            s4v lv = {f2bt(v0 - b2f(h0)), f2bt(v1 - b2f(h1)),
                      f2bt(v2 - b2f(h2)), f2bt(v3 - b2f(h3))};
            int chb = 32 * w + 16 * i + 4 * quad;
            *reinterpret_cast<s4v*>(hhi + px * 272 + chb) = hv;
            *reinterpret_cast<s4v*>(hlo + px * 272 + chb) = lv;
        }
    }
    bar_lgkm();

    // ---- flow GEMM: wave (dg = w&3, ph = w>>2) -> dirs [16dg,16dg+16)
    //      over px-half [32ph, 32ph+32) ----
    const int dg = w & 3;
    const int ph = w >> 2;
    f4v acc_f[2];
    #pragma unroll
    for (int j = 0; j < 2; ++j) acc_f[j] = (f4v){0.f, 0.f, 0.f, 0.f};
    #pragma unroll
    for (int c = 0; c < 8; ++c) {
        const size_t wb = ((size_t)c * 64 + 16 * dg + lr) * 32 + quad8;
        s8v ahi = *reinterpret_cast<const s8v*>(w2thi + wb);
        s8v alo = *reinterpret_cast<const s8v*>(w2tlo + wb);
        #pragma unroll
        for (int j = 0; j < 2; ++j) {
            int px = 32 * ph + 16 * j + lr;
            s8v bhh = *reinterpret_cast<const s8v*>(hhi + px * 272 + c * 32 + quad8);
            s8v bll = *reinterpret_cast<const s8v*>(hlo + px * 272 + c * 32 + quad8);
            acc_f[j] = __builtin_amdgcn_mfma_f32_16x16x32_bf16(ahi, bhh, acc_f[j], 0, 0, 0);
            acc_f[j] = __builtin_amdgcn_mfma_f32_16x16x32_bf16(ahi, bll, acc_f[j], 0, 0, 0);
            acc_f[j] = __builtin_amdgcn_mfma_f32_16x16x32_bf16(alo, bhh, acc_f[j], 0, 0, 0);
        }
    }
    float4 b2v = *reinterpret_cast<const float4*>(b2 + 16 * dg + 4 * quad);
    #pragma unroll
    for (int r = 0; r < 4; ++r) {
        int dir = 16 * dg + 4 * quad + r;
        float bias = (r == 0) ? b2v.x : (r == 1) ? b2v.y : (r == 2) ? b2v.z : b2v.w;
        #pragma unroll
        for (int j = 0; j < 2; ++j)
            flow[((size_t)b * 64 + dir) * HW + p0 + 32 * ph + 16 * j + lr] = acc_f[j][r] + bias;
    }
}

// ---------------- k_warp: bilinear gather from bf16 head-major value ---------
// XCD-swizzled: all 64 blocks of one (b,head) land on the same XCD (bid%8),
// so the head's 256 KB vbuf slice + its 2 flow rows stay L2-resident there.
__global__ __launch_bounds__(256) void k_warp(
    const float* __restrict__ flow, const unsigned short* __restrict__ vbuf,
    float* __restrict__ out)
{
    const int bid = blockIdx.x;       // 8192
    const int xcd = bid & 7;
    const int k   = bid >> 3;         // 0..1023
    const int n   = xcd * 16 + (k >> 6);            // 0..127 = b*32+head
    const int p   = ((k & 63) << 8) + threadIdx.x;  // 0..16383
    const int b = n >> 5;
    const int head = n & 31;
    const int y = p >> 7;
    const int x = p & 127;

    float fx = flow[((size_t)b * 64 + 2 * head + 0) * HW + p];
    float fy = flow[((size_t)b * 64 + 2 * head + 1) * HW + p];
    float ix = (float)x + fx * 63.5f;
    float iy = (float)y + fy * 63.5f;

    float x0f = floorf(ix), y0f = floorf(iy);
    float dx = ix - x0f, dy = iy - y0f;
    int x0 = (int)x0f, y0 = (int)y0f;
    int x1 = x0 + 1,   y1 = y0 + 1;

    bool vx0 = (x0 >= 0) & (x0 < 128);
    bool vx1 = (x1 >= 0) & (x1 < 128);
    bool vy0 = (y0 >= 0) & (y0 < 128);
    bool vy1 = (y1 >= 0) & (y1 < 128);
    int x0c = min(max(x0, 0), 127), x1c = min(max(x1, 0), 127);
    int y0c = min(max(y0, 0), 127), y1c = min(max(y1, 0), 127);

    float w00 = (1.f - dx) * (1.f - dy) * ((vx0 & vy0) ? 1.f : 0.f);
    float w10 = dx * (1.f - dy)        * ((vx1 & vy0) ? 1.f : 0.f);
    float w01 = (1.f - dx) * dy        * ((vx0 & vy1) ? 1.f : 0.f);
    float w11 = dx * dy                * ((vx1 & vy1) ? 1.f : 0.f);

    const unsigned short* vb = vbuf + (((size_t)n) << 14) * 8;
    s8v v00 = *reinterpret_cast<const s8v*>(vb + (size_t)(y0c * 128 + x0c) * 8);
    s8v v10 = *reinterpret_cast<const s8v*>(vb + (size_t)(y0c * 128 + x1c) * 8);
    s8v v01 = *reinterpret_cast<const s8v*>(vb + (size_t)(y1c * 128 + x0c) * 8);
    s8v v11 = *reinterpret_cast<const s8v*>(vb + (size_t)(y1c * 128 + x1c) * 8);

    float* ob = out + ((size_t)b * 256 + head * 8) * HW + p;
    #pragma unroll
    for (int ci = 0; ci < 8; ++ci) {
        float v = w00 * b2f(v00[ci]) + w10 * b2f(v10[ci])
                + w01 * b2f(v01[ci]) + w11 * b2f(v11[ci]);
        ob[(size_t)ci * HW] = v;
    }
}

extern "C" void kernel_launch(void* const* d_in, const int* in_sizes, int n_in,
                              void* d_out, int out_size, void* d_ws, size_t ws_size,
                              hipStream_t stream) {
    const float* u  = (const float*)d_in[0];
    const float* w1 = (const float*)d_in[1];
    const float* b1 = (const float*)d_in[2];
    const float* w2 = (const float*)d_in[3];
    const float* b2 = (const float*)d_in[4];
    const float* wv = (const float*)d_in[5];
    const float* bv = (const float*)d_in[6];

    char* ws = (char*)d_ws;
    unsigned short* vbuf = (unsigned short*)ws;                 // 33.5 MB
    float* flow  = (float*)(ws + 33554432ull);                  // 16.8 MB
    short* Wthi  = (short*)(ws + 50331648ull);                  // 131072 el
    short* Wtlo  = Wthi + 131072;                               // 65536 el
    short* w2thi = Wtlo + 65536;                                // 16384 el
    short* w2tlo = w2thi + 16384;                               // 16384 el
    float* out = (float*)d_out;

    k_prep_w<<<dim3(576),  dim3(256), 0, stream>>>(w1, wv, w2, Wthi, Wtlo, w2thi, w2tlo);
    k_mega  <<<dim3(1024), dim3(512), 0, stream>>>(u, Wthi, Wtlo, w2thi, w2tlo,
                                                   b1, bv, b2, vbuf, flow);
    k_warp  <<<dim3(8192), dim3(256), 0, stream>>>(flow, vbuf, out);
}

// Round 4
// 207.251 us; speedup vs baseline: 1.1299x; 1.1299x over previous
//
#include <hip/hip_runtime.h>
#include <cstddef>

#define HW 16384

typedef short s8v __attribute__((ext_vector_type(8)));
typedef short s4v __attribute__((ext_vector_type(4)));
typedef float f4v __attribute__((ext_vector_type(4)));

__device__ inline short f2b(float x) {
    union { float f; unsigned u; } v; v.f = x;
    unsigned r = v.u + 0x7fff + ((v.u >> 16) & 1);
    return (short)(r >> 16);
}
// truncating bf16 — for lo residuals only (error ~2^-17 of value)
__device__ inline short f2bt(float x) {
    union { float f; unsigned u; } v; v.f = x;
    return (short)(v.u >> 16);
}
__device__ inline float b2f(short h) {
    union { unsigned u; float f; } v;
    v.u = ((unsigned)(unsigned short)h) << 16;
    return v.f;
}

// Barrier that does NOT drain vmcnt: LDS hazards only need lgkmcnt(0).
__device__ inline void bar_lgkm() {
    asm volatile("s_waitcnt lgkmcnt(0)\n\ts_barrier" ::: "memory");
}

// ---------------- k_prep_w: weights -> chunk-tiled bf16 hi/lo ----------------
__global__ __launch_bounds__(256) void k_prep_w(
    const float* __restrict__ w1, const float* __restrict__ wv,
    const float* __restrict__ w2,
    short* __restrict__ Wthi, short* __restrict__ Wtlo,
    short* __restrict__ w2thi, short* __restrict__ w2tlo)
{
    int tid = blockIdx.x * 256 + threadIdx.x;   // 0..147455
    if (tid < 131072) {
        int c = tid >> 14, r = tid & 16383, ch = r >> 5, kk = r & 31;
        float f = (ch < 256) ? w1[ch * 256 + c * 32 + kk]
                             : wv[(ch - 256) * 256 + c * 32 + kk];
        short hi = f2b(f);
        Wthi[tid] = hi;
        if (ch < 256) Wtlo[(c * 256 + ch) * 32 + kk] = f2b(f - b2f(hi));
    } else {
        int o = tid - 131072;                   // 0..16383
        int c = o >> 11, r = o & 2047, dir = r >> 5, kk = r & 31;
        float f = w2[dir * 256 + c * 32 + kk];
        short hi = f2b(f);
        w2thi[o] = hi;
        w2tlo[o] = f2b(f - b2f(hi));
    }
}

// ---------------- k_mega: fused h(split) + value + flow per 32-px block ------
// R4: 32-px tile, 256 threads / 4 waves. Wave w owns h-ch [64w,64w+64) (split
// hi/lo, 3 MFMA) + value-ch [64w,64w+64) (hi only) over 32 px.
// acc = acc_h[4][2] + acc_v[4][2] = 64 regs; arch ~100 -> total <=168 ->
// 3 waves/SIMD (3 blocks/CU; LDS 34.8 KB x3 = 104 KB). This is the spill-free
// occupancy raise R3 failed at (R3: 128-reg cap -> 240 MB scratch traffic).
__global__ __launch_bounds__(256, 3) void k_mega(
    const float* __restrict__ u,
    const short* __restrict__ Wthi, const short* __restrict__ Wtlo,
    const short* __restrict__ w2thi, const short* __restrict__ w2tlo,
    const float* __restrict__ b1, const float* __restrict__ bv,
    const float* __restrict__ b2,
    unsigned short* __restrict__ vbuf, float* __restrict__ flow)
{
    __shared__ __attribute__((aligned(16))) char smem[34816];
    short* T1h = (short*)smem;               // 64ch x 36, 4608 B
    short* T1l = T1h + 2304;                 // ends 9216
    short* T2h = (short*)(smem + 9216);      // 32px x 72, 4608 B
    short* T2l = T2h + 2304;                 // ends 18432
    short* vt  = (short*)smem;               // 32px x 272 = 17408 B (post K-loop)
    short* hhi = (short*)smem;               // 17408 B (post value store)
    short* hlo = (short*)(smem + 17408);     // ends 34816

    const int t = threadIdx.x;               // 0..255
    const int l = t & 63;
    const int w = t >> 6;                    // wave 0..3
    const int lr = l & 15;
    const int quad = l >> 4;
    const int quad8 = quad * 8;
    const int h5 = l >> 5;
    const int pxB = l & 31;                  // stage-B pixel
    const int pt = blockIdx.x * 32;
    const int b  = pt >> 14;
    const int p0 = pt & 16383;
    const float* ub = u + (size_t)b * 256 * HW + p0;

    f4v acc_h[4][2], acc_v[4][2];
    #pragma unroll
    for (int i = 0; i < 4; ++i)
        #pragma unroll
        for (int j = 0; j < 2; ++j) {
            acc_h[i][j] = (f4v){0.f, 0.f, 0.f, 0.f};
            acc_v[i][j] = (f4v){0.f, 0.f, 0.f, 0.f};
        }

    float4 cur[2];
    auto loadU = [&](int pr) {
        #pragma unroll
        for (int i = 0; i < 2; ++i) {
            int idx = t + 256 * i;           // 0..511
            int ch = idx >> 3, px4 = (idx & 7) * 4;
            cur[i] = *reinterpret_cast<const float4*>(
                ub + (size_t)(pr * 64 + ch) * HW + px4);
        }
    };
    // stage A: convert+split cur -> T1 [ch][px] (stride 36)
    auto stageA = [&]() {
        #pragma unroll
        for (int i = 0; i < 2; ++i) {
            int idx = t + 256 * i;
            int ch = idx >> 3, px4 = (idx & 7) * 4;
            float4 v = cur[i];
            short h0 = f2b(v.x), h1 = f2b(v.y), h2 = f2b(v.z), h3 = f2b(v.w);
            s4v hv = {h0, h1, h2, h3};
            s4v lv = {f2bt(v.x - b2f(h0)), f2bt(v.y - b2f(h1)),
                      f2bt(v.z - b2f(h2)), f2bt(v.w - b2f(h3))};
            *reinterpret_cast<s4v*>(T1h + ch * 36 + px4) = hv;
            *reinterpret_cast<s4v*>(T1l + ch * 36 + px4) = lv;
        }
    };
    // stage B: transpose T1 -> T2 [px][k] (stride 72). Lane: px = l&31,
    // half h5 = l>>5; wave w covers k4 = 4w + 2*h5 + j, j in 0..1.
    auto stageB = [&]() {
        #pragma unroll
        for (int part = 0; part < 2; ++part) {
            const short* src = part ? T1l : T1h;
            short* dst = part ? T2l : T2h;
            #pragma unroll
            for (int j = 0; j < 2; ++j) {
                int k4 = 4 * w + 2 * h5 + j;
                s4v v = { src[(4 * k4 + 0) * 36 + pxB],
                          src[(4 * k4 + 1) * 36 + pxB],
                          src[(4 * k4 + 2) * 36 + pxB],
                          src[(4 * k4 + 3) * 36 + pxB] };
                *reinterpret_cast<s4v*>(dst + pxB * 72 + 4 * k4) = v;
            }
        }
    };

    loadU(0);
    for (int pair = 0; pair < 4; ++pair) {
        stageA();
        bar_lgkm();
        stageB();
        bar_lgkm();
        if (pair < 3) loadU(pair + 1);   // overlaps MFMA (vmcnt not drained)
        #pragma unroll
        for (int s = 0; s < 2; ++s) {
            int c = pair * 2 + s;
            s8v bh4[2], bl4[2];
            #pragma unroll
            for (int j = 0; j < 2; ++j) {
                bh4[j] = *reinterpret_cast<const s8v*>(T2h + (16 * j + lr) * 72 + s * 32 + quad8);
                bl4[j] = *reinterpret_cast<const s8v*>(T2l + (16 * j + lr) * 72 + s * 32 + quad8);
            }
            #pragma unroll
            for (int i = 0; i < 4; ++i) {
                const size_t wb = ((size_t)c * 512 + 64 * w + 16 * i + lr) * 32 + quad8;
                s8v ahi = *reinterpret_cast<const s8v*>(Wthi + wb);
                s8v av  = *reinterpret_cast<const s8v*>(Wthi + wb + 256 * 32);
                s8v alo = *reinterpret_cast<const s8v*>(
                    Wtlo + ((size_t)c * 256 + 64 * w + 16 * i + lr) * 32 + quad8);
                #pragma unroll
                for (int j = 0; j < 2; ++j) {
                    acc_h[i][j] = __builtin_amdgcn_mfma_f32_16x16x32_bf16(ahi, bh4[j], acc_h[i][j], 0, 0, 0);
                    acc_h[i][j] = __builtin_amdgcn_mfma_f32_16x16x32_bf16(ahi, bl4[j], acc_h[i][j], 0, 0, 0);
                    acc_h[i][j] = __builtin_amdgcn_mfma_f32_16x16x32_bf16(alo, bh4[j], acc_h[i][j], 0, 0, 0);
                    acc_v[i][j] = __builtin_amdgcn_mfma_f32_16x16x32_bf16(av,  bh4[j], acc_v[i][j], 0, 0, 0);
                }
            }
        }
        bar_lgkm();   // T2 reads done before next pair's T1/T2 writes
    }

    // ---- value epilogue: accs -> vt LDS -> head-major bf16 stores ----
    #pragma unroll
    for (int i = 0; i < 4; ++i) {
        float4 bias = *reinterpret_cast<const float4*>(bv + 64 * w + 16 * i + 4 * quad);
        #pragma unroll
        for (int j = 0; j < 2; ++j) {
            int px = 16 * j + lr;
            s4v pk = { f2b(acc_v[i][j][0] + bias.x), f2b(acc_v[i][j][1] + bias.y),
                       f2b(acc_v[i][j][2] + bias.z), f2b(acc_v[i][j][3] + bias.w) };
            *reinterpret_cast<s4v*>(vt + px * 272 + 64 * w + 16 * i + 4 * quad) = pk;
        }
    }
    bar_lgkm();
    {
        // vbuf layout: [(b*32+head)][pix][8ch] -> 16B per (head,pixel)
        int px = t >> 3;              // 0..31
        int hg = t & 7;               // 4 heads per thread
        size_t pix = (size_t)p0 + px;
        #pragma unroll
        for (int e = 0; e < 4; ++e) {
            int hh = hg + 8 * e;
            s8v vv = *reinterpret_cast<const s8v*>(vt + px * 272 + hh * 8);
            *reinterpret_cast<s8v*>(
                vbuf + ((((size_t)(b * 32 + hh)) << 14) + pix) * 8) = vv;
        }
    }
    bar_lgkm();   // vt reads done before h overwrites

    // ---- h epilogue: bias+relu, split -> hhi/hlo LDS [px][272] ----
    #pragma unroll
    for (int i = 0; i < 4; ++i) {
        float4 bias = *reinterpret_cast<const float4*>(b1 + 64 * w + 16 * i + 4 * quad);
        #pragma unroll
        for (int j = 0; j < 2; ++j) {
            int px = 16 * j + lr;
            float v0 = fmaxf(acc_h[i][j][0] + bias.x, 0.f);
            float v1 = fmaxf(acc_h[i][j][1] + bias.y, 0.f);
            float v2 = fmaxf(acc_h[i][j][2] + bias.z, 0.f);
            float v3 = fmaxf(acc_h[i][j][3] + bias.w, 0.f);
            short h0 = f2b(v0), h1 = f2b(v1), h2 = f2b(v2), h3 = f2b(v3);
            s4v hv = {h0, h1, h2, h3};
            s4v lv = {f2bt(v0 - b2f(h0)), f2bt(v1 - b2f(h1)),
                      f2bt(v2 - b2f(h2)), f2bt(v3 - b2f(h3))};
            int chb = 64 * w + 16 * i + 4 * quad;
            *reinterpret_cast<s4v*>(hhi + px * 272 + chb) = hv;
            *reinterpret_cast<s4v*>(hlo + px * 272 + chb) = lv;
        }
    }
    bar_lgkm();

    // ---- flow GEMM: wave w -> dirs [16w,16w+16) over 32 px ----
    f4v acc_f[2];
    #pragma unroll
    for (int j = 0; j < 2; ++j) acc_f[j] = (f4v){0.f, 0.f, 0.f, 0.f};
    #pragma unroll
    for (int c = 0; c < 8; ++c) {
        const size_t wb = ((size_t)c * 64 + 16 * w + lr) * 32 + quad8;
        s8v ahi = *reinterpret_cast<const s8v*>(w2thi + wb);
        s8v alo = *reinterpret_cast<const s8v*>(w2tlo + wb);
        #pragma unroll
        for (int j = 0; j < 2; ++j) {
            int px = 16 * j + lr;
            s8v bhh = *reinterpret_cast<const s8v*>(hhi + px * 272 + c * 32 + quad8);
            s8v bll = *reinterpret_cast<const s8v*>(hlo + px * 272 + c * 32 + quad8);
            acc_f[j] = __builtin_amdgcn_mfma_f32_16x16x32_bf16(ahi, bhh, acc_f[j], 0, 0, 0);
            acc_f[j] = __builtin_amdgcn_mfma_f32_16x16x32_bf16(ahi, bll, acc_f[j], 0, 0, 0);
            acc_f[j] = __builtin_amdgcn_mfma_f32_16x16x32_bf16(alo, bhh, acc_f[j], 0, 0, 0);
        }
    }
    float4 b2v = *reinterpret_cast<const float4*>(b2 + 16 * w + 4 * quad);
    #pragma unroll
    for (int r = 0; r < 4; ++r) {
        int dir = 16 * w + 4 * quad + r;
        float bias = (r == 0) ? b2v.x : (r == 1) ? b2v.y : (r == 2) ? b2v.z : b2v.w;
        #pragma unroll
        for (int j = 0; j < 2; ++j)
            flow[((size_t)b * 64 + dir) * HW + p0 + 16 * j + lr] = acc_f[j][r] + bias;
    }
}

// ---------------- k_warp: bilinear gather from bf16 head-major value ---------
// XCD-swizzled: all 64 blocks of one (b,head) land on the same XCD (bid%8),
// so the head's 256 KB vbuf slice + its 2 flow rows stay L2-resident there.
__global__ __launch_bounds__(256) void k_warp(
    const float* __restrict__ flow, const unsigned short* __restrict__ vbuf,
    float* __restrict__ out)
{
    const int bid = blockIdx.x;       // 8192
    const int xcd = bid & 7;
    const int k   = bid >> 3;         // 0..1023
    const int n   = xcd * 16 + (k >> 6);            // 0..127 = b*32+head
    const int p   = ((k & 63) << 8) + threadIdx.x;  // 0..16383
    const int b = n >> 5;
    const int head = n & 31;
    const int y = p >> 7;
    const int x = p & 127;

    float fx = flow[((size_t)b * 64 + 2 * head + 0) * HW + p];
    float fy = flow[((size_t)b * 64 + 2 * head + 1) * HW + p];
    float ix = (float)x + fx * 63.5f;
    float iy = (float)y + fy * 63.5f;

    float x0f = floorf(ix), y0f = floorf(iy);
    float dx = ix - x0f, dy = iy - y0f;
    int x0 = (int)x0f, y0 = (int)y0f;
    int x1 = x0 + 1,   y1 = y0 + 1;

    bool vx0 = (x0 >= 0) & (x0 < 128);
    bool vx1 = (x1 >= 0) & (x1 < 128);
    bool vy0 = (y0 >= 0) & (y0 < 128);
    bool vy1 = (y1 >= 0) & (y1 < 128);
    int x0c = min(max(x0, 0), 127), x1c = min(max(x1, 0), 127);
    int y0c = min(max(y0, 0), 127), y1c = min(max(y1, 0), 127);

    float w00 = (1.f - dx) * (1.f - dy) * ((vx0 & vy0) ? 1.f : 0.f);
    float w10 = dx * (1.f - dy)        * ((vx1 & vy0) ? 1.f : 0.f);
    float w01 = (1.f - dx) * dy        * ((vx0 & vy1) ? 1.f : 0.f);
    float w11 = dx * dy                * ((vx1 & vy1) ? 1.f : 0.f);

    const unsigned short* vb = vbuf + (((size_t)n) << 14) * 8;
    s8v v00 = *reinterpret_cast<const s8v*>(vb + (size_t)(y0c * 128 + x0c) * 8);
    s8v v10 = *reinterpret_cast<const s8v*>(vb + (size_t)(y0c * 128 + x1c) * 8);
    s8v v01 = *reinterpret_cast<const s8v*>(vb + (size_t)(y1c * 128 + x0c) * 8);
    s8v v11 = *reinterpret_cast<const s8v*>(vb + (size_t)(y1c * 128 + x1c) * 8);

    float* ob = out + ((size_t)b * 256 + head * 8) * HW + p;
    #pragma unroll
    for (int ci = 0; ci < 8; ++ci) {
        float v = w00 * b2f(v00[ci]) + w10 * b2f(v10[ci])
                + w01 * b2f(v01[ci]) + w11 * b2f(v11[ci]);
        ob[(size_t)ci * HW] = v;
    }
}

extern "C" void kernel_launch(void* const* d_in, const int* in_sizes, int n_in,
                              void* d_out, int out_size, void* d_ws, size_t ws_size,
                              hipStream_t stream) {
    const float* u  = (const float*)d_in[0];
    const float* w1 = (const float*)d_in[1];
    const float* b1 = (const float*)d_in[2];
    const float* w2 = (const float*)d_in[3];
    const float* b2 = (const float*)d_in[4];
    const float* wv = (const float*)d_in[5];
    const float* bv = (const float*)d_in[6];

    char* ws = (char*)d_ws;
    unsigned short* vbuf = (unsigned short*)ws;                 // 33.5 MB
    float* flow  = (float*)(ws + 33554432ull);                  // 16.8 MB
    short* Wthi  = (short*)(ws + 50331648ull);                  // 131072 el
    short* Wtlo  = Wthi + 131072;                               // 65536 el
    short* w2thi = Wtlo + 65536;                                // 16384 el
    short* w2tlo = w2thi + 16384;                               // 16384 el
    float* out = (float*)d_out;

    k_prep_w<<<dim3(576),  dim3(256), 0, stream>>>(w1, wv, w2, Wthi, Wtlo, w2thi, w2tlo);
    k_mega  <<<dim3(2048), dim3(256), 0, stream>>>(u, Wthi, Wtlo, w2thi, w2tlo,
                                                   b1, bv, b2, vbuf, flow);
    k_warp  <<<dim3(8192), dim3(256), 0, stream>>>(flow, vbuf, out);
}

// Round 5
// 191.743 us; speedup vs baseline: 1.2213x; 1.0809x over previous
//
#include <hip/hip_runtime.h>
#include <cstddef>

#define HW 16384

typedef short s8v __attribute__((ext_vector_type(8)));
typedef short s4v __attribute__((ext_vector_type(4)));
typedef float f4v __attribute__((ext_vector_type(4)));

__device__ inline short f2b(float x) {
    union { float f; unsigned u; } v; v.f = x;
    unsigned r = v.u + 0x7fff + ((v.u >> 16) & 1);
    return (short)(r >> 16);
}
// truncating bf16 — for lo residuals only (error ~2^-17 of value)
__device__ inline short f2bt(float x) {
    union { float f; unsigned u; } v; v.f = x;
    return (short)(v.u >> 16);
}
__device__ inline float b2f(short h) {
    union { unsigned u; float f; } v;
    v.u = ((unsigned)(unsigned short)h) << 16;
    return v.f;
}

// Barrier that does NOT drain vmcnt: LDS hazards only need lgkmcnt(0).
__device__ inline void bar_lgkm() {
    asm volatile("s_waitcnt lgkmcnt(0)\n\ts_barrier" ::: "memory");
}

// ---------------- k_prep_w: weights -> chunk-tiled bf16 hi/lo ----------------
__global__ __launch_bounds__(256) void k_prep_w(
    const float* __restrict__ w1, const float* __restrict__ wv,
    const float* __restrict__ w2,
    short* __restrict__ Wthi, short* __restrict__ Wtlo,
    short* __restrict__ w2thi, short* __restrict__ w2tlo)
{
    int tid = blockIdx.x * 256 + threadIdx.x;   // 0..147455
    if (tid < 131072) {
        int c = tid >> 14, r = tid & 16383, ch = r >> 5, kk = r & 31;
        float f = (ch < 256) ? w1[ch * 256 + c * 32 + kk]
                             : wv[(ch - 256) * 256 + c * 32 + kk];
        short hi = f2b(f);
        Wthi[tid] = hi;
        if (ch < 256) Wtlo[(c * 256 + ch) * 32 + kk] = f2b(f - b2f(hi));
    } else {
        int o = tid - 131072;                   // 0..16383
        int c = o >> 11, r = o & 2047, dir = r >> 5, kk = r & 31;
        float f = w2[dir * 256 + c * 32 + kk];
        short hi = f2b(f);
        w2thi[o] = hi;
        w2tlo[o] = f2b(f - b2f(hi));
    }
}

// ---------------- k_mega: R1-best config restored --------------------------
// 64-px blocks, 256 threads / 4 waves, 2 blocks/CU. Wave w owns h-ch
// [64w,64w+64) (split hi/lo, 3 MFMA) + value-ch [64w,64w+64) (hi only).
// R3/R4 evidence: raising occupancy (3-4 waves/SIMD) LOSES to this config —
// per-wave amortization (16 MFMA per A-frag triple, 12 barriers per 512
// MFMAs) dominates. Weight A-frags pipelined 1 step; lgkm-only barriers keep
// them in flight.
__global__ __launch_bounds__(256, 2) void k_mega(
    const float* __restrict__ u,
    const short* __restrict__ Wthi, const short* __restrict__ Wtlo,
    const short* __restrict__ w2thi, const short* __restrict__ w2tlo,
    const float* __restrict__ b1, const float* __restrict__ bv,
    const float* __restrict__ b2,
    unsigned short* __restrict__ vbuf, float* __restrict__ flow)
{
    __shared__ __attribute__((aligned(16))) char smem[69632];
    short* T1h = (short*)smem;               // 64ch x 68, 8704 B
    short* T1l = T1h + 4352;                 // ends 17408
    short* T2h = (short*)(smem + 17408);     // 64px x 72, 9216 B
    short* T2l = T2h + 4608;                 // ends 35840
    short* vt  = (short*)smem;               // 64px x 272 = 34816 B (post K-loop)
    short* hhi = (short*)smem;               // 34816 B (post value store)
    short* hlo = (short*)(smem + 34816);     // ends 69632

    const int t = threadIdx.x;
    const int l = t & 63;
    const int w = t >> 6;
    const int lr = l & 15;
    const int quad = l >> 4;
    const int quad8 = quad * 8;
    const int pt = blockIdx.x * 64;
    const int b  = pt >> 14;
    const int p0 = pt & 16383;
    const float* ub = u + (size_t)b * 256 * HW + p0;
    const int pxB = 16 * w + lr;             // stage-B pixel

    f4v acc_h[4][4], acc_v[4][4];
    #pragma unroll
    for (int i = 0; i < 4; ++i)
        #pragma unroll
        for (int j = 0; j < 4; ++j) {
            acc_h[i][j] = (f4v){0.f, 0.f, 0.f, 0.f};
            acc_v[i][j] = (f4v){0.f, 0.f, 0.f, 0.f};
        }

    // preload pair 0 (64 k-channels of u for our 64 pixels)
    float4 cur[4];
    #pragma unroll
    for (int i = 0; i < 4; ++i) {
        int idx = t + 256 * i;
        int ch = idx >> 4, px4 = (idx & 15) * 4;
        cur[i] = *reinterpret_cast<const float4*>(ub + (size_t)ch * HW + px4);
    }

    // prime A-frag pipeline: step (c=0, i=0)
    s8v nx_hi, nx_v, nx_lo;
    {
        const size_t wb0 = ((size_t)(64 * w + lr)) * 32 + quad8;
        nx_hi = *reinterpret_cast<const s8v*>(Wthi + wb0);
        nx_v  = *reinterpret_cast<const s8v*>(Wthi + wb0 + 256 * 32);
        nx_lo = *reinterpret_cast<const s8v*>(Wtlo + wb0);
    }

    for (int pair = 0; pair < 4; ++pair) {
        // ---- stage A: convert+split into T1 [ch][px] (stride 68) ----
        #pragma unroll
        for (int i = 0; i < 4; ++i) {
            int idx = t + 256 * i;
            int ch = idx >> 4, px4 = (idx & 15) * 4;
            float4 v = cur[i];
            short h0 = f2b(v.x), h1 = f2b(v.y), h2 = f2b(v.z), h3 = f2b(v.w);
            s4v hv = {h0, h1, h2, h3};
            s4v lv = {f2bt(v.x - b2f(h0)), f2bt(v.y - b2f(h1)),
                      f2bt(v.z - b2f(h2)), f2bt(v.w - b2f(h3))};
            *reinterpret_cast<s4v*>(T1h + ch * 68 + px4) = hv;
            *reinterpret_cast<s4v*>(T1l + ch * 68 + px4) = lv;
        }
        bar_lgkm();
        // ---- stage B: transpose T1 -> T2 [px][k] (stride 72) ----
        #pragma unroll
        for (int part = 0; part < 2; ++part) {
            const short* src = part ? T1l : T1h;
            short* dst = part ? T2l : T2h;
            #pragma unroll
            for (int j = 0; j < 4; ++j) {
                int k4 = quad + 4 * j;
                s4v v = { src[(4 * k4 + 0) * 68 + pxB],
                          src[(4 * k4 + 1) * 68 + pxB],
                          src[(4 * k4 + 2) * 68 + pxB],
                          src[(4 * k4 + 3) * 68 + pxB] };
                *reinterpret_cast<s4v*>(dst + pxB * 72 + 4 * k4) = v;
            }
        }
        bar_lgkm();
        // prefetch next pair of u (overlaps MFMA; vmcnt not drained)
        if (pair < 3) {
            #pragma unroll
            for (int i = 0; i < 4; ++i) {
                int idx = t + 256 * i;
                int ch = idx >> 4, px4 = (idx & 15) * 4;
                cur[i] = *reinterpret_cast<const float4*>(
                    ub + (size_t)((pair + 1) * 64 + ch) * HW + px4);
            }
        }
        // ---- MFMA: 2 k32-steps, A-frags pipelined 1 step ahead ----
        #pragma unroll
        for (int s = 0; s < 2; ++s) {
            int c = pair * 2 + s;
            s8v bh4[4], bl4[4];
            #pragma unroll
            for (int j = 0; j < 4; ++j) {
                bh4[j] = *reinterpret_cast<const s8v*>(T2h + (16 * j + lr) * 72 + s * 32 + quad8);
                bl4[j] = *reinterpret_cast<const s8v*>(T2l + (16 * j + lr) * 72 + s * 32 + quad8);
            }
            #pragma unroll
            for (int i = 0; i < 4; ++i) {
                s8v ahi = nx_hi, av = nx_v, alo = nx_lo;
                {   // issue next step's weight loads (wraps harmlessly)
                    int idx = c * 4 + i + 1;
                    int ni = idx & 3;
                    int nc = (idx >> 2) & 7;
                    const size_t wb = ((size_t)nc * 512 + 64 * w + 16 * ni + lr) * 32 + quad8;
                    nx_hi = *reinterpret_cast<const s8v*>(Wthi + wb);
                    nx_v  = *reinterpret_cast<const s8v*>(Wthi + wb + 256 * 32);
                    nx_lo = *reinterpret_cast<const s8v*>(
                        Wtlo + ((size_t)nc * 256 + 64 * w + 16 * ni + lr) * 32 + quad8);
                }
                #pragma unroll
                for (int j = 0; j < 4; ++j) {
                    acc_h[i][j] = __builtin_amdgcn_mfma_f32_16x16x32_bf16(ahi, bh4[j], acc_h[i][j], 0, 0, 0);
                    acc_h[i][j] = __builtin_amdgcn_mfma_f32_16x16x32_bf16(ahi, bl4[j], acc_h[i][j], 0, 0, 0);
                    acc_h[i][j] = __builtin_amdgcn_mfma_f32_16x16x32_bf16(alo, bh4[j], acc_h[i][j], 0, 0, 0);
                    acc_v[i][j] = __builtin_amdgcn_mfma_f32_16x16x32_bf16(av,  bh4[j], acc_v[i][j], 0, 0, 0);
                }
            }
        }
        bar_lgkm();   // T2 reads done before next pair's T1/T2 writes
    }

    // ---- value epilogue: accs -> vt LDS -> head-major bf16 stores ----
    #pragma unroll
    for (int i = 0; i < 4; ++i) {
        float4 bias = *reinterpret_cast<const float4*>(bv + 64 * w + 16 * i + 4 * quad);
        #pragma unroll
        for (int j = 0; j < 4; ++j) {
            int px = 16 * j + lr;
            s4v pk = { f2b(acc_v[i][j][0] + bias.x), f2b(acc_v[i][j][1] + bias.y),
                       f2b(acc_v[i][j][2] + bias.z), f2b(acc_v[i][j][3] + bias.w) };
            *reinterpret_cast<s4v*>(vt + px * 272 + 64 * w + 16 * i + 4 * quad) = pk;
        }
    }
    bar_lgkm();
    {
        // vbuf layout: [(b*32+head)][pix][8ch] -> 16B per (head,pixel)
        int px = t >> 2;              // 0..63
        int h0 = (t & 3) * 8;         // 8 heads per thread
        size_t pix = (size_t)p0 + px;
        #pragma unroll
        for (int e = 0; e < 8; ++e) {
            int hh = h0 + e;
            s8v vv = *reinterpret_cast<const s8v*>(vt + px * 272 + hh * 8);
            *reinterpret_cast<s8v*>(
                vbuf + ((((size_t)(b * 32 + hh)) << 14) + pix) * 8) = vv;
        }
    }
    bar_lgkm();   // vt reads done before h overwrites

    // ---- h epilogue: bias+relu, split -> hhi/hlo LDS [px][272] ----
    #pragma unroll
    for (int i = 0; i < 4; ++i) {
        float4 bias = *reinterpret_cast<const float4*>(b1 + 64 * w + 16 * i + 4 * quad);
        #pragma unroll
        for (int j = 0; j < 4; ++j) {
            int px = 16 * j + lr;
            float v0 = fmaxf(acc_h[i][j][0] + bias.x, 0.f);
            float v1 = fmaxf(acc_h[i][j][1] + bias.y, 0.f);
            float v2 = fmaxf(acc_h[i][j][2] + bias.z, 0.f);
            float v3 = fmaxf(acc_h[i][j][3] + bias.w, 0.f);
            short h0 = f2b(v0), h1 = f2b(v1), h2 = f2b(v2), h3 = f2b(v3);
            s4v hv = {h0, h1, h2, h3};
            s4v lv = {f2bt(v0 - b2f(h0)), f2bt(v1 - b2f(h1)),
                      f2bt(v2 - b2f(h2)), f2bt(v3 - b2f(h3))};
            int chb = 64 * w + 16 * i + 4 * quad;
            *reinterpret_cast<s4v*>(hhi + px * 272 + chb) = hv;
            *reinterpret_cast<s4v*>(hlo + px * 272 + chb) = lv;
        }
    }
    // prime flow-GEMM A-frag pipeline before the barrier
    s8v f_hi, f_lo;
    {
        const size_t wb = ((size_t)(16 * w + lr)) * 32 + quad8;
        f_hi = *reinterpret_cast<const s8v*>(w2thi + wb);
        f_lo = *reinterpret_cast<const s8v*>(w2tlo + wb);
    }
    bar_lgkm();

    // ---- flow GEMM: wave w -> dirs [16w,16w+16), split bf16 (3 MFMA) ----
    f4v acc_f[4];
    #pragma unroll
    for (int j = 0; j < 4; ++j) acc_f[j] = (f4v){0.f, 0.f, 0.f, 0.f};
    #pragma unroll
    for (int c = 0; c < 8; ++c) {
        s8v ahi = f_hi, alo = f_lo;
        {
            int ncf = (c + 1) & 7;
            const size_t wb = ((size_t)ncf * 64 + 16 * w + lr) * 32 + quad8;
            f_hi = *reinterpret_cast<const s8v*>(w2thi + wb);
            f_lo = *reinterpret_cast<const s8v*>(w2tlo + wb);
        }
        #pragma unroll
        for (int j = 0; j < 4; ++j) {
            int px = 16 * j + lr;
            s8v bhh = *reinterpret_cast<const s8v*>(hhi + px * 272 + c * 32 + quad8);
            s8v bll = *reinterpret_cast<const s8v*>(hlo + px * 272 + c * 32 + quad8);
            acc_f[j] = __builtin_amdgcn_mfma_f32_16x16x32_bf16(ahi, bhh, acc_f[j], 0, 0, 0);
            acc_f[j] = __builtin_amdgcn_mfma_f32_16x16x32_bf16(ahi, bll, acc_f[j], 0, 0, 0);
            acc_f[j] = __builtin_amdgcn_mfma_f32_16x16x32_bf16(alo, bhh, acc_f[j], 0, 0, 0);
        }
    }
    // flow stored interleaved: float2 (fx,fy) at [(b*32+head)][p].
    // dirs 16w+4quad+{0,1} -> head0 = 8w+2quad comp {x,y}; +{2,3} -> head0+1.
    float4 b2v = *reinterpret_cast<const float4*>(b2 + 16 * w + 4 * quad);
    float2* fl2 = reinterpret_cast<float2*>(flow);
    const int head0 = 8 * w + 2 * quad;
    #pragma unroll
    for (int j = 0; j < 4; ++j) {
        int p = p0 + 16 * j + lr;
        float2 f01 = { acc_f[j][0] + b2v.x, acc_f[j][1] + b2v.y };
        float2 f23 = { acc_f[j][2] + b2v.z, acc_f[j][3] + b2v.w };
        fl2[(size_t)(b * 32 + head0) * HW + p] = f01;
        fl2[(size_t)(b * 32 + head0 + 1) * HW + p] = f23;
    }
}

// ---------------- k_warp: bilinear gather, 2 px/thread ----------------------
// flow read as one coalesced float2; 8 gathers in flight per thread (2x MLP);
// out written as float2 (8B/lane coalesced) -> halves store instructions on
// the 268 MB output stream. XCD-swizzled: 16 heads per XCD, each head's
// 256 KB vbuf slice L2-resident.
__global__ __launch_bounds__(256) void k_warp(
    const float* __restrict__ flow, const unsigned short* __restrict__ vbuf,
    float* __restrict__ out)
{
    const int bid = blockIdx.x;                 // 0..4095
    const int xcd = bid & 7;
    const int idx = bid >> 3;                   // 0..511
    const int n   = xcd * 16 + (idx >> 5);      // 0..127 = b*32+head
    const int blk = idx & 31;                   // 0..31
    const int p   = (blk << 9) + (threadIdx.x << 1);  // even, 0..16382
    const int b = n >> 5;
    const int head = n & 31;

    const float2* fl2 = reinterpret_cast<const float2*>(flow) + (size_t)n * HW;
    const unsigned short* vb = vbuf + (((size_t)n) << 14) * 8;

    float vals[8][2];
    #pragma unroll
    for (int e = 0; e < 2; ++e) {
        int pp = p + e;
        int y = pp >> 7;
        int x = pp & 127;
        float2 fv = fl2[pp];
        float ix = (float)x + fv.x * 63.5f;
        float iy = (float)y + fv.y * 63.5f;

        float x0f = floorf(ix), y0f = floorf(iy);
        float dx = ix - x0f, dy = iy - y0f;
        int x0 = (int)x0f, y0 = (int)y0f;
        int x1 = x0 + 1,   y1 = y0 + 1;

        bool vx0 = (x0 >= 0) & (x0 < 128);
        bool vx1 = (x1 >= 0) & (x1 < 128);
        bool vy0 = (y0 >= 0) & (y0 < 128);
        bool vy1 = (y1 >= 0) & (y1 < 128);
        int x0c = min(max(x0, 0), 127), x1c = min(max(x1, 0), 127);
        int y0c = min(max(y0, 0), 127), y1c = min(max(y1, 0), 127);

        float w00 = (1.f - dx) * (1.f - dy) * ((vx0 & vy0) ? 1.f : 0.f);
        float w10 = dx * (1.f - dy)        * ((vx1 & vy0) ? 1.f : 0.f);
        float w01 = (1.f - dx) * dy        * ((vx0 & vy1) ? 1.f : 0.f);
        float w11 = dx * dy                * ((vx1 & vy1) ? 1.f : 0.f);

        s8v v00 = *reinterpret_cast<const s8v*>(vb + (size_t)(y0c * 128 + x0c) * 8);
        s8v v10 = *reinterpret_cast<const s8v*>(vb + (size_t)(y0c * 128 + x1c) * 8);
        s8v v01 = *reinterpret_cast<const s8v*>(vb + (size_t)(y1c * 128 + x0c) * 8);
        s8v v11 = *reinterpret_cast<const s8v*>(vb + (size_t)(y1c * 128 + x1c) * 8);

        #pragma unroll
        for (int ci = 0; ci < 8; ++ci) {
            vals[ci][e] = w00 * b2f(v00[ci]) + w10 * b2f(v10[ci])
                        + w01 * b2f(v01[ci]) + w11 * b2f(v11[ci]);
        }
    }

    float* ob = out + ((size_t)b * 256 + head * 8) * HW + p;
    #pragma unroll
    for (int ci = 0; ci < 8; ++ci) {
        float2 o2 = { vals[ci][0], vals[ci][1] };
        *reinterpret_cast<float2*>(ob + (size_t)ci * HW) = o2;
    }
}

extern "C" void kernel_launch(void* const* d_in, const int* in_sizes, int n_in,
                              void* d_out, int out_size, void* d_ws, size_t ws_size,
                              hipStream_t stream) {
    const float* u  = (const float*)d_in[0];
    const float* w1 = (const float*)d_in[1];
    const float* b1 = (const float*)d_in[2];
    const float* w2 = (const float*)d_in[3];
    const float* b2 = (const float*)d_in[4];
    const float* wv = (const float*)d_in[5];
    const float* bv = (const float*)d_in[6];

    char* ws = (char*)d_ws;
    unsigned short* vbuf = (unsigned short*)ws;                 // 33.5 MB
    float* flow  = (float*)(ws + 33554432ull);                  // 16.8 MB (float2/head/px)
    short* Wthi  = (short*)(ws + 50331648ull);                  // 131072 el
    short* Wtlo  = Wthi + 131072;                               // 65536 el
    short* w2thi = Wtlo + 65536;                                // 16384 el
    short* w2tlo = w2thi + 16384;                               // 16384 el
    float* out = (float*)d_out;

    k_prep_w<<<dim3(576),  dim3(256), 0, stream>>>(w1, wv, w2, Wthi, Wtlo, w2thi, w2tlo);
    k_mega  <<<dim3(1024), dim3(256), 0, stream>>>(u, Wthi, Wtlo, w2thi, w2tlo,
                                                   b1, bv, b2, vbuf, flow);
    k_warp  <<<dim3(4096), dim3(256), 0, stream>>>(flow, vbuf, out);
}

// Round 6
// 180.612 us; speedup vs baseline: 1.2966x; 1.0616x over previous
//
#include <hip/hip_runtime.h>
#include <cstddef>

#define HW 16384

typedef short s8v __attribute__((ext_vector_type(8)));
typedef short s4v __attribute__((ext_vector_type(4)));
typedef float f4v __attribute__((ext_vector_type(4)));

__device__ inline short f2b(float x) {
    union { float f; unsigned u; } v; v.f = x;
    unsigned r = v.u + 0x7fff + ((v.u >> 16) & 1);
    return (short)(r >> 16);
}
__device__ inline float b2f(short h) {
    union { unsigned u; float f; } v;
    v.u = ((unsigned)(unsigned short)h) << 16;
    return v.f;
}

// Barrier that does NOT drain vmcnt: LDS hazards only need lgkmcnt(0).
// Keeps prefetched global loads (weights, u tiles) in flight across it.
__device__ inline void bar_lgkm() {
    asm volatile("s_waitcnt lgkmcnt(0)\n\ts_barrier" ::: "memory");
}

// ---------------- k_prep_w: weights -> chunk-tiled bf16 hi/lo ----------------
__global__ __launch_bounds__(256) void k_prep_w(
    const float* __restrict__ w1, const float* __restrict__ wv,
    const float* __restrict__ w2,
    short* __restrict__ Wthi, short* __restrict__ Wtlo,
    short* __restrict__ w2thi, short* __restrict__ w2tlo)
{
    int tid = blockIdx.x * 256 + threadIdx.x;   // 0..147455
    if (tid < 131072) {
        int c = tid >> 14, r = tid & 16383, ch = r >> 5, kk = r & 31;
        float f = (ch < 256) ? w1[ch * 256 + c * 32 + kk]
                             : wv[(ch - 256) * 256 + c * 32 + kk];
        short hi = f2b(f);
        Wthi[tid] = hi;
        if (ch < 256) Wtlo[(c * 256 + ch) * 32 + kk] = f2b(f - b2f(hi));
    } else {
        int o = tid - 131072;                   // 0..16383
        int c = o >> 11, r = o & 2047, dir = r >> 5, kk = r & 31;
        float f = w2[dir * 256 + c * 32 + kk];
        short hi = f2b(f);
        w2thi[o] = hi;
        w2tlo[o] = f2b(f - b2f(hi));
    }
}

// ---------------- k_mega: EXACT R1 source (measured 69.7 us) -----------------
// 64-px blocks, 256 threads, 2 blocks/CU, VGPR 120 (NO spill — R5's f2bt +
// interleaved-flow epilogue pushed VGPR to 128 => 10 MB scratch => 94 us).
// Do not touch register pressure here without watching VGPR_Count/WRITE_SIZE.
__global__ __launch_bounds__(256, 2) void k_mega(
    const float* __restrict__ u,
    const short* __restrict__ Wthi, const short* __restrict__ Wtlo,
    const short* __restrict__ w2thi, const short* __restrict__ w2tlo,
    const float* __restrict__ b1, const float* __restrict__ bv,
    const float* __restrict__ b2,
    unsigned short* __restrict__ vbuf, float* __restrict__ flow)
{
    __shared__ __attribute__((aligned(16))) char smem[69632];
    short* T1h = (short*)smem;               // 64ch x 68, 8704 B
    short* T1l = T1h + 4352;                 // ends 17408
    short* T2h = (short*)(smem + 17408);     // 64px x 72, 9216 B
    short* T2l = T2h + 4608;                 // ends 35840
    short* vt  = (short*)smem;               // 64px x 272 = 34816 B (post K-loop)
    short* hhi = (short*)smem;               // 34816 B (post value store)
    short* hlo = (short*)(smem + 34816);     // ends 69632

    const int t = threadIdx.x;
    const int l = t & 63;
    const int w = t >> 6;
    const int lr = l & 15;
    const int quad = l >> 4;
    const int quad8 = quad * 8;
    const int pt = blockIdx.x * 64;
    const int b  = pt >> 14;
    const int p0 = pt & 16383;
    const float* ub = u + (size_t)b * 256 * HW + p0;
    const int pxB = 16 * w + lr;             // stage-B pixel

    f4v acc_h[4][4], acc_v[4][4];
    #pragma unroll
    for (int i = 0; i < 4; ++i)
        #pragma unroll
        for (int j = 0; j < 4; ++j) {
            acc_h[i][j] = (f4v){0.f, 0.f, 0.f, 0.f};
            acc_v[i][j] = (f4v){0.f, 0.f, 0.f, 0.f};
        }

    // preload pair 0 (64 k-channels of u for our 64 pixels)
    float4 cur[4];
    #pragma unroll
    for (int i = 0; i < 4; ++i) {
        int idx = t + 256 * i;
        int ch = idx >> 4, px4 = (idx & 15) * 4;
        cur[i] = *reinterpret_cast<const float4*>(ub + (size_t)ch * HW + px4);
    }

    // prime A-frag pipeline: step (c=0, i=0)
    s8v nx_hi, nx_v, nx_lo;
    {
        const size_t wb0 = ((size_t)(64 * w + lr)) * 32 + quad8;
        nx_hi = *reinterpret_cast<const s8v*>(Wthi + wb0);
        nx_v  = *reinterpret_cast<const s8v*>(Wthi + wb0 + 256 * 32);
        nx_lo = *reinterpret_cast<const s8v*>(Wtlo + wb0);
    }

    for (int pair = 0; pair < 4; ++pair) {
        // ---- stage A: convert+split into T1 [ch][px] (stride 68) ----
        #pragma unroll
        for (int i = 0; i < 4; ++i) {
            int idx = t + 256 * i;
            int ch = idx >> 4, px4 = (idx & 15) * 4;
            float4 v = cur[i];
            short h0 = f2b(v.x), h1 = f2b(v.y), h2 = f2b(v.z), h3 = f2b(v.w);
            s4v hv = {h0, h1, h2, h3};
            s4v lv = {f2b(v.x - b2f(h0)), f2b(v.y - b2f(h1)),
                      f2b(v.z - b2f(h2)), f2b(v.w - b2f(h3))};
            *reinterpret_cast<s4v*>(T1h + ch * 68 + px4) = hv;
            *reinterpret_cast<s4v*>(T1l + ch * 68 + px4) = lv;
        }
        bar_lgkm();
        // ---- stage B: transpose T1 -> T2 [px][k] (stride 72) ----
        #pragma unroll
        for (int part = 0; part < 2; ++part) {
            const short* src = part ? T1l : T1h;
            short* dst = part ? T2l : T2h;
            #pragma unroll
            for (int j = 0; j < 4; ++j) {
                int k4 = (l >> 4) + 4 * j;
                s4v v = { src[(4 * k4 + 0) * 68 + pxB],
                          src[(4 * k4 + 1) * 68 + pxB],
                          src[(4 * k4 + 2) * 68 + pxB],
                          src[(4 * k4 + 3) * 68 + pxB] };
                *reinterpret_cast<s4v*>(dst + pxB * 72 + 4 * k4) = v;
            }
        }
        bar_lgkm();
        // prefetch next pair of u (overlaps MFMA)
        if (pair < 3) {
            #pragma unroll
            for (int i = 0; i < 4; ++i) {
                int idx = t + 256 * i;
                int ch = idx >> 4, px4 = (idx & 15) * 4;
                cur[i] = *reinterpret_cast<const float4*>(
                    ub + (size_t)((pair + 1) * 64 + ch) * HW + px4);
            }
        }
        // ---- MFMA: 2 k32-steps, A-frags pipelined 1 step ahead ----
        #pragma unroll
        for (int s = 0; s < 2; ++s) {
            int c = pair * 2 + s;
            s8v bh4[4], bl4[4];
            #pragma unroll
            for (int j = 0; j < 4; ++j) {
                bh4[j] = *reinterpret_cast<const s8v*>(T2h + (16 * j + lr) * 72 + s * 32 + quad8);
                bl4[j] = *reinterpret_cast<const s8v*>(T2l + (16 * j + lr) * 72 + s * 32 + quad8);
            }
            #pragma unroll
            for (int i = 0; i < 4; ++i) {
                s8v ahi = nx_hi, av = nx_v, alo = nx_lo;
                {   // issue next step's weight loads (wraps harmlessly)
                    int idx = c * 4 + i + 1;
                    int ni = idx & 3;
                    int nc = (idx >> 2) & 7;
                    const size_t wb = ((size_t)nc * 512 + 64 * w + 16 * ni + lr) * 32 + quad8;
                    nx_hi = *reinterpret_cast<const s8v*>(Wthi + wb);
                    nx_v  = *reinterpret_cast<const s8v*>(Wthi + wb + 256 * 32);
                    nx_lo = *reinterpret_cast<const s8v*>(
                        Wtlo + ((size_t)nc * 256 + 64 * w + 16 * ni + lr) * 32 + quad8);
                }
                #pragma unroll
                for (int j = 0; j < 4; ++j) {
                    acc_h[i][j] = __builtin_amdgcn_mfma_f32_16x16x32_bf16(ahi, bh4[j], acc_h[i][j], 0, 0, 0);
                    acc_h[i][j] = __builtin_amdgcn_mfma_f32_16x16x32_bf16(ahi, bl4[j], acc_h[i][j], 0, 0, 0);
                    acc_h[i][j] = __builtin_amdgcn_mfma_f32_16x16x32_bf16(alo, bh4[j], acc_h[i][j], 0, 0, 0);
                    acc_v[i][j] = __builtin_amdgcn_mfma_f32_16x16x32_bf16(av,  bh4[j], acc_v[i][j], 0, 0, 0);
                }
            }
        }
        bar_lgkm();   // T2 reads done before next pair's T1/T2 writes
    }

    // ---- value epilogue: accs -> vt LDS -> head-major bf16 stores ----
    #pragma unroll
    for (int i = 0; i < 4; ++i) {
        float4 bias = *reinterpret_cast<const float4*>(bv + 64 * w + 16 * i + 4 * quad);
        #pragma unroll
        for (int j = 0; j < 4; ++j) {
            int px = 16 * j + lr;
            s4v pk = { f2b(acc_v[i][j][0] + bias.x), f2b(acc_v[i][j][1] + bias.y),
                       f2b(acc_v[i][j][2] + bias.z), f2b(acc_v[i][j][3] + bias.w) };
            *reinterpret_cast<s4v*>(vt + px * 272 + 64 * w + 16 * i + 4 * quad) = pk;
        }
    }
    bar_lgkm();
    {
        // vbuf layout: [(b*32+head)][pix][8ch] -> 16B per (head,pixel)
        int px = t >> 2;              // 0..63
        int h0 = (t & 3) * 8;         // 8 heads per thread
        size_t pix = (size_t)p0 + px;
        #pragma unroll
        for (int e = 0; e < 8; ++e) {
            int hh = h0 + e;
            s8v vv = *reinterpret_cast<const s8v*>(vt + px * 272 + hh * 8);
            *reinterpret_cast<s8v*>(
                vbuf + ((((size_t)(b * 32 + hh)) << 14) + pix) * 8) = vv;
        }
    }
    bar_lgkm();   // vt reads done before h overwrites

    // ---- h epilogue: bias+relu, split -> hhi/hlo LDS [px][272] ----
    #pragma unroll
    for (int i = 0; i < 4; ++i) {
        float4 bias = *reinterpret_cast<const float4*>(b1 + 64 * w + 16 * i + 4 * quad);
        #pragma unroll
        for (int j = 0; j < 4; ++j) {
            int px = 16 * j + lr;
            float v0 = fmaxf(acc_h[i][j][0] + bias.x, 0.f);
            float v1 = fmaxf(acc_h[i][j][1] + bias.y, 0.f);
            float v2 = fmaxf(acc_h[i][j][2] + bias.z, 0.f);
            float v3 = fmaxf(acc_h[i][j][3] + bias.w, 0.f);
            short h0 = f2b(v0), h1 = f2b(v1), h2 = f2b(v2), h3 = f2b(v3);
            s4v hv = {h0, h1, h2, h3};
            s4v lv = {f2b(v0 - b2f(h0)), f2b(v1 - b2f(h1)),
                      f2b(v2 - b2f(h2)), f2b(v3 - b2f(h3))};
            int chb = 64 * w + 16 * i + 4 * quad;
            *reinterpret_cast<s4v*>(hhi + px * 272 + chb) = hv;
            *reinterpret_cast<s4v*>(hlo + px * 272 + chb) = lv;
        }
    }
    // prime flow-GEMM A-frag pipeline (issued before barrier: latency hides
    // under the barrier wait + first B-frag LDS reads)
    s8v f_hi, f_lo;
    {
        const size_t wb = ((size_t)(16 * w + lr)) * 32 + quad8;
        f_hi = *reinterpret_cast<const s8v*>(w2thi + wb);
        f_lo = *reinterpret_cast<const s8v*>(w2tlo + wb);
    }
    bar_lgkm();

    // ---- flow GEMM: wave w -> dirs [16w,16w+16), split bf16 (3 MFMA) ----
    f4v acc_f[4];
    #pragma unroll
    for (int j = 0; j < 4; ++j) acc_f[j] = (f4v){0.f, 0.f, 0.f, 0.f};
    #pragma unroll
    for (int c = 0; c < 8; ++c) {
        s8v ahi = f_hi, alo = f_lo;
        {
            int ncf = (c + 1) & 7;
            const size_t wb = ((size_t)ncf * 64 + 16 * w + lr) * 32 + quad8;
            f_hi = *reinterpret_cast<const s8v*>(w2thi + wb);
            f_lo = *reinterpret_cast<const s8v*>(w2tlo + wb);
        }
        #pragma unroll
        for (int j = 0; j < 4; ++j) {
            int px = 16 * j + lr;
            s8v bhh = *reinterpret_cast<const s8v*>(hhi + px * 272 + c * 32 + quad8);
            s8v bll = *reinterpret_cast<const s8v*>(hlo + px * 272 + c * 32 + quad8);
            acc_f[j] = __builtin_amdgcn_mfma_f32_16x16x32_bf16(ahi, bhh, acc_f[j], 0, 0, 0);
            acc_f[j] = __builtin_amdgcn_mfma_f32_16x16x32_bf16(ahi, bll, acc_f[j], 0, 0, 0);
            acc_f[j] = __builtin_amdgcn_mfma_f32_16x16x32_bf16(alo, bhh, acc_f[j], 0, 0, 0);
        }
    }
    float4 b2v = *reinterpret_cast<const float4*>(b2 + 16 * w + 4 * quad);
    #pragma unroll
    for (int r = 0; r < 4; ++r) {
        int dir = 16 * w + 4 * quad + r;
        float bias = (r == 0) ? b2v.x : (r == 1) ? b2v.y : (r == 2) ? b2v.z : b2v.w;
        #pragma unroll
        for (int j = 0; j < 4; ++j)
            flow[((size_t)b * 64 + dir) * HW + p0 + 16 * j + lr] = acc_f[j][r] + bias;
    }
}

// ---------------- k_warp: bilinear gather, 2 px/thread ----------------------
// Dir-major flow: the thread's 2 adjacent pixels read fx as ONE float2 from
// the fx-row and fy as ONE float2 from the fy-row (same bytes/lane as the
// interleaved layout, but needs no k_mega epilogue change). 8 gathers in
// flight (2x MLP); float2 out-stores; XCD-swizzled (16 heads/XCD, vbuf slice
// L2-resident).
__global__ __launch_bounds__(256) void k_warp(
    const float* __restrict__ flow, const unsigned short* __restrict__ vbuf,
    float* __restrict__ out)
{
    const int bid = blockIdx.x;                 // 0..4095
    const int xcd = bid & 7;
    const int idx = bid >> 3;                   // 0..511
    const int n   = xcd * 16 + (idx >> 5);      // 0..127 = b*32+head
    const int blk = idx & 31;                   // 0..31
    const int p   = (blk << 9) + (threadIdx.x << 1);  // even, 0..16382
    const int b = n >> 5;
    const int head = n & 31;

    const float* fxrow = flow + ((size_t)b * 64 + 2 * head) * HW;
    float2 fx2 = *reinterpret_cast<const float2*>(fxrow + p);
    float2 fy2 = *reinterpret_cast<const float2*>(fxrow + HW + p);
    const unsigned short* vb = vbuf + (((size_t)n) << 14) * 8;

    float vals[8][2];
    #pragma unroll
    for (int e = 0; e < 2; ++e) {
        int pp = p + e;
        int y = pp >> 7;
        int x = pp & 127;
        float fx = e ? fx2.y : fx2.x;
        float fy = e ? fy2.y : fy2.x;
        float ix = (float)x + fx * 63.5f;
        float iy = (float)y + fy * 63.5f;

        float x0f = floorf(ix), y0f = floorf(iy);
        float dx = ix - x0f, dy = iy - y0f;
        int x0 = (int)x0f, y0 = (int)y0f;
        int x1 = x0 + 1,   y1 = y0 + 1;

        bool vx0 = (x0 >= 0) & (x0 < 128);
        bool vx1 = (x1 >= 0) & (x1 < 128);
        bool vy0 = (y0 >= 0) & (y0 < 128);
        bool vy1 = (y1 >= 0) & (y1 < 128);
        int x0c = min(max(x0, 0), 127), x1c = min(max(x1, 0), 127);
        int y0c = min(max(y0, 0), 127), y1c = min(max(y1, 0), 127);

        float w00 = (1.f - dx) * (1.f - dy) * ((vx0 & vy0) ? 1.f : 0.f);
        float w10 = dx * (1.f - dy)        * ((vx1 & vy0) ? 1.f : 0.f);
        float w01 = (1.f - dx) * dy        * ((vx0 & vy1) ? 1.f : 0.f);
        float w11 = dx * dy                * ((vx1 & vy1) ? 1.f : 0.f);

        s8v v00 = *reinterpret_cast<const s8v*>(vb + (size_t)(y0c * 128 + x0c) * 8);
        s8v v10 = *reinterpret_cast<const s8v*>(vb + (size_t)(y0c * 128 + x1c) * 8);
        s8v v01 = *reinterpret_cast<const s8v*>(vb + (size_t)(y1c * 128 + x0c) * 8);
        s8v v11 = *reinterpret_cast<const s8v*>(vb + (size_t)(y1c * 128 + x1c) * 8);

        #pragma unroll
        for (int ci = 0; ci < 8; ++ci) {
            vals[ci][e] = w00 * b2f(v00[ci]) + w10 * b2f(v10[ci])
                        + w01 * b2f(v01[ci]) + w11 * b2f(v11[ci]);
        }
    }

    float* ob = out + ((size_t)b * 256 + head * 8) * HW + p;
    #pragma unroll
    for (int ci = 0; ci < 8; ++ci) {
        float2 o2 = { vals[ci][0], vals[ci][1] };
        *reinterpret_cast<float2*>(ob + (size_t)ci * HW) = o2;
    }
}

extern "C" void kernel_launch(void* const* d_in, const int* in_sizes, int n_in,
                              void* d_out, int out_size, void* d_ws, size_t ws_size,
                              hipStream_t stream) {
    const float* u  = (const float*)d_in[0];
    const float* w1 = (const float*)d_in[1];
    const float* b1 = (const float*)d_in[2];
    const float* w2 = (const float*)d_in[3];
    const float* b2 = (const float*)d_in[4];
    const float* wv = (const float*)d_in[5];
    const float* bv = (const float*)d_in[6];

    char* ws = (char*)d_ws;
    unsigned short* vbuf = (unsigned short*)ws;                 // 33.5 MB
    float* flow  = (float*)(ws + 33554432ull);                  // 16.8 MB
    short* Wthi  = (short*)(ws + 50331648ull);                  // 131072 el
    short* Wtlo  = Wthi + 131072;                               // 65536 el
    short* w2thi = Wtlo + 65536;                                // 16384 el
    short* w2tlo = w2thi + 16384;                               // 16384 el
    float* out = (float*)d_out;

    k_prep_w<<<dim3(576),  dim3(256), 0, stream>>>(w1, wv, w2, Wthi, Wtlo, w2thi, w2tlo);
    k_mega  <<<dim3(1024), dim3(256), 0, stream>>>(u, Wthi, Wtlo, w2thi, w2tlo,
                                                   b1, bv, b2, vbuf, flow);
    k_warp  <<<dim3(4096), dim3(256), 0, stream>>>(flow, vbuf, out);
}